// Round 4
// baseline (1431.343 us; speedup 1.0000x reference)
//
#include <hip/hip_runtime.h>
#include <stdint.h>

// Self-attention, SEQ=8192, D=768, single head.
//   K0a: x fp32->bf16; K0b: Wq/Wk/Wv fp32->bf16 (z-fused)
//   K1a: Q,K projections z-fused (MODE 0); K1b: Vt = Wv x^T (MODE 0)
//   K2 : P' = exp(Q K^T) bf16 + atomic row sums (MODE 1)
//   K3 : out += (P'_chunk V)/rowsum, split-K x4, fp32 atomicAdd (MODE 2)
//
// R14 == R12 resubmitted (R2/R3 benches were container-acquisition infra
// failures; the kernel never ran. Audit found no container-killing path:
// gload_lds dest is wave-uniform+lane*16 [m104, same helper ran in R11],
// bounds fit, barriers uniform, 32KB x 5 blk/CU = legal 160KB).
// R12 = R8's proven staging (LINEAR global_load_lds width=16, no swizzle
// anywhere) + R11's occupancy win (single 32 KB linear LDS buffer -> 5
// blk/CU; R8 had 36 KB pad -> 3.2) + hoisted K-invariant read offsets.
// R11 POST-MORTEM: a 16B-granule 3-bit XOR on the global SOURCE destroyed
// DMA coalescing (FETCH 66MB -> 1.8GB, K2 157 -> 1065us). Source must stay
// lane-linear. Bank conflicts (1.26e7) are measured NOT on the critical
// path in this 2-barrier structure (R8 == R10 despite 1.26e7 vs 0), so we
// accept them rather than pay coalescing for them.
// This is exactly the m97 structure (874 TF at 4096^3 bf16, 128^2 tile,
// BK=64, single buffer, 2 lgkm barriers + vmcnt drain at barrier #2,
// hidden by 5 blocks/CU of TLP).

#define SEQ    8192
#define DMODEL 768
#define KSPLIT 4
#define LROW   64            // LDS row stride in halfwords (128 B, linear)

typedef short bf16x8 __attribute__((ext_vector_type(8)));
typedef float f32x4  __attribute__((ext_vector_type(4)));
typedef float f32x16 __attribute__((ext_vector_type(16)));

__device__ __forceinline__ unsigned short f2bf(float f) {
  union { float f; unsigned int u; } v; v.f = f;
  unsigned int u = v.u;
  u += 0x7FFFu + ((u >> 16) & 1u);   // round-to-nearest-even
  return (unsigned short)(u >> 16);
}

// global -> LDS direct DMA, 16 B per lane. LDS dest is wave-uniform base +
// lane*16 (m104); global source is lane-linear (coalescing-critical, R11!).
__device__ __forceinline__ void gload16(const unsigned short* g, unsigned short* l) {
  __builtin_amdgcn_global_load_lds(
      (const __attribute__((address_space(1))) unsigned int*)g,
      (__attribute__((address_space(3))) unsigned int*)l, 16, 0, 0);
}

__global__ void convert_x(const float* __restrict__ src,
                          unsigned short* __restrict__ dst, int n4) {
  int i = blockIdx.x * blockDim.x + threadIdx.x;
  if (i >= n4) return;
  const float4 f = ((const float4*)src)[i];
  ushort4 o;
  o.x = f2bf(f.x); o.y = f2bf(f.y); o.z = f2bf(f.z); o.w = f2bf(f.w);
  ((ushort4*)dst)[i] = o;
}

__global__ void convert_w(const float* __restrict__ s0, const float* __restrict__ s1,
                          const float* __restrict__ s2,
                          unsigned short* __restrict__ d0, unsigned short* __restrict__ d1,
                          unsigned short* __restrict__ d2, int n4) {
  const float* s = (blockIdx.z == 0) ? s0 : (blockIdx.z == 1) ? s1 : s2;
  unsigned short* d = (blockIdx.z == 0) ? d0 : (blockIdx.z == 1) ? d1 : d2;
  int i = blockIdx.x * blockDim.x + threadIdx.x;
  if (i >= n4) return;
  const float4 f = ((const float4*)s)[i];
  ushort4 o;
  o.x = f2bf(f.x); o.y = f2bf(f.y); o.z = f2bf(f.z); o.w = f2bf(f.w);
  ((ushort4*)d)[i] = o;
}

// C[m,n] = sum_k A[m,k]*B[n,k]  (A:[M,K], B:[N,K] bf16 row-major)
// GRID: blockIdx.x = M-tile, blockIdx.y = N-tile (same-A blocks -> same XCD)
// BK=64, SINGLE linear LDS buffer [128][64] per tensor (32 KB total).
// K-step: compute(kt) -> barrier (reads done) -> issue 8 gload_lds(kt+1)
//   -> barrier (vmcnt drain; hidden by TLP at 5 blk/CU) -> next.
// MFMA 32x32x16: wave quadrant 64x64 = 2x2 tiles; A-op row=lane&31,
// k=(lane>>5)*8+j; C/D col=lane&31, row=(reg&3)+8*(reg>>2)+4*(lane>>5)
// [m74/m101 HW-verified].
// MODE 0: bf16 C*alpha; z=1 uses B2/Cout2/alpha2 (QK fusion)
// MODE 1: bf16 exp(C) + atomicAdd per-row exp-sums into rowsum
// MODE 2: split-K over z (kChunk each); atomicAdd fp32 C/rowsum[m] into Cout
template <int MODE>
__launch_bounds__(256, 5)
__global__ void gemm_bt(const unsigned short* __restrict__ A,
                        const unsigned short* __restrict__ B,
                        void* __restrict__ Cout,
                        int M, int N, int K, float alpha,
                        float* __restrict__ rowsum, int kChunk,
                        const unsigned short* __restrict__ B2,
                        void* __restrict__ Cout2, float alpha2) {
  __shared__ __align__(16) unsigned short lA[128 * LROW];
  __shared__ __align__(16) unsigned short lB[128 * LROW];

  if (MODE == 0) {
    if (blockIdx.z == 1) { B = B2; Cout = Cout2; alpha = alpha2; }
  }
  const int kOff = (MODE == 2) ? blockIdx.z * kChunk : 0;

  const int t    = threadIdx.x;
  const int w    = t >> 6;
  const int l    = t & 63;
  const int r32  = l & 31;     // row within a 32-tile / output col
  const int kh   = l >> 5;     // k-half selector
  const int m0   = blockIdx.x * 128;
  const int n0   = blockIdx.y * 128;
  const int wm   = (w & 1) * 64;
  const int wn   = (w >> 1) * 64;

  // Staging map: 1024 16B-chunks per tensor, 4/thread. c = t + h*256:
  // row = c>>3, 16B-slot j = c&7. Fully LINEAR on both sides:
  // LDS dest chunk c -> byte c*16 (wave-uniform base + lane*16);
  // global source = row*K + j*16B (lane-linear per 128B row).
  int gOff[4], dOff[4];
#pragma unroll
  for (int h = 0; h < 4; ++h) {
    int c   = t + (h << 8);
    gOff[h] = (c >> 3) * K + ((c & 7) << 3);   // + m0*K / n0*K in base ptrs
    dOff[h] = c << 3;                          // linear halfword offset
  }
  const unsigned short* Abase = A + (size_t)m0 * K + kOff;
  const unsigned short* Bbase = B + (size_t)n0 * K + kOff;

  // K-invariant read offsets (halfwords), hoisted out of the K-loop.
  int offA0[4], offA1[4], offB0[4], offB1[4];
#pragma unroll
  for (int ks = 0; ks < 4; ++ks) {
    const int gg = ((ks << 1) | kh) << 3;
    offA0[ks] = (wm      + r32) * LROW + gg;
    offA1[ks] = (wm + 32 + r32) * LROW + gg;
    offB0[ks] = (wn      + r32) * LROW + gg;
    offB1[ks] = (wn + 32 + r32) * LROW + gg;
  }

  f32x16 acc[2][2] = {};
  const int nk = kChunk >> 6;

  // Prologue: DMA tile 0, drain, go.
#pragma unroll
  for (int h = 0; h < 4; ++h) gload16(Abase + gOff[h], &lA[dOff[h]]);
#pragma unroll
  for (int h = 0; h < 4; ++h) gload16(Bbase + gOff[h], &lB[dOff[h]]);
  __syncthreads();                      // vmcnt(0) drain -> tile 0 resident

  for (int kt = 0; kt < nk; ++kt) {
#pragma unroll
    for (int ks = 0; ks < 4; ++ks) {
      bf16x8 a0 = *(const bf16x8*)&lA[offA0[ks]];
      bf16x8 a1 = *(const bf16x8*)&lA[offA1[ks]];
      bf16x8 b0 = *(const bf16x8*)&lB[offB0[ks]];
      bf16x8 b1 = *(const bf16x8*)&lB[offB1[ks]];
      acc[0][0] = __builtin_amdgcn_mfma_f32_32x32x16_bf16(a0, b0, acc[0][0], 0, 0, 0);
      acc[0][1] = __builtin_amdgcn_mfma_f32_32x32x16_bf16(a0, b1, acc[0][1], 0, 0, 0);
      acc[1][0] = __builtin_amdgcn_mfma_f32_32x32x16_bf16(a1, b0, acc[1][0], 0, 0, 0);
      acc[1][1] = __builtin_amdgcn_mfma_f32_32x32x16_bf16(a1, b1, acc[1][1], 0, 0, 0);
    }
    if (kt + 1 < nk) {
      __syncthreads();                  // all reads of the buffer done
      const int ko = (kt + 1) << 6;
#pragma unroll
      for (int h = 0; h < 4; ++h) gload16(Abase + gOff[h] + ko, &lA[dOff[h]]);
#pragma unroll
      for (int h = 0; h < 4; ++h) gload16(Bbase + gOff[h] + ko, &lB[dOff[h]]);
      __syncthreads();                  // vmcnt drain -> tile kt+1 resident
    }
  }

  // C/D 32x32 (m74/m101): col = lane&31, row = (reg&3) + 8*(reg>>2) + 4*kh
  if (MODE == 0) {
    unsigned short* C = (unsigned short*)Cout;
#pragma unroll
    for (int mi = 0; mi < 2; ++mi)
#pragma unroll
      for (int reg = 0; reg < 16; ++reg) {
        int m = m0 + wm + mi * 32 + (reg & 3) + ((reg >> 2) << 3) + (kh << 2);
#pragma unroll
        for (int ni = 0; ni < 2; ++ni) {
          int n = n0 + wn + ni * 32 + r32;
          C[(size_t)m * N + n] = f2bf(acc[mi][ni][reg] * alpha);
        }
      }
  } else if (MODE == 1) {
    unsigned short* C = (unsigned short*)Cout;
#pragma unroll
    for (int mi = 0; mi < 2; ++mi)
#pragma unroll
      for (int reg = 0; reg < 16; ++reg) {
        int m = m0 + wm + mi * 32 + (reg & 3) + ((reg >> 2) << 3) + (kh << 2);
        float s = 0.f;
#pragma unroll
        for (int ni = 0; ni < 2; ++ni) {
          int n = n0 + wn + ni * 32 + r32;
          float p = __expf(acc[mi][ni][reg]);
          C[(size_t)m * N + n] = f2bf(p);
          s += p;
        }
        // reduce over the 32 lanes (r32) sharing this row
#pragma unroll
        for (int off = 1; off < 32; off <<= 1) s += __shfl_xor(s, off, 64);
        if (r32 == 0) atomicAdd(&rowsum[m], s);
      }
  } else {
    float* C = (float*)Cout;   // d_out fp32, zero-initialized; split-K partials
#pragma unroll
    for (int mi = 0; mi < 2; ++mi)
#pragma unroll
      for (int reg = 0; reg < 16; ++reg) {
        int m = m0 + wm + mi * 32 + (reg & 3) + ((reg >> 2) << 3) + (kh << 2);
        float inv = 1.0f / rowsum[m];
#pragma unroll
        for (int ni = 0; ni < 2; ++ni) {
          int n = n0 + wn + ni * 32 + r32;
          atomicAdd(&C[(size_t)m * N + n], acc[mi][ni][reg] * inv);
        }
      }
  }
}

extern "C" void kernel_launch(void* const* d_in, const int* in_sizes, int n_in,
                              void* d_out, int out_size, void* d_ws, size_t ws_size,
                              hipStream_t stream) {
  const float* x  = (const float*)d_in[0];
  const float* Wq = (const float*)d_in[1];
  const float* Wk = (const float*)d_in[2];
  const float* Wv = (const float*)d_in[3];

  char* ws = (char*)d_ws;
  unsigned short* xb     = (unsigned short*)(ws + 0);
  unsigned short* Qb     = (unsigned short*)(ws + 12582912);
  unsigned short* Kb     = (unsigned short*)(ws + 25165824);
  unsigned short* Vtb    = (unsigned short*)(ws + 37748736);
  unsigned short* wqb    = (unsigned short*)(ws + 50331648);
  unsigned short* wkb    = (unsigned short*)(ws + 51511296);
  unsigned short* wvb    = (unsigned short*)(ws + 52690944);
  float*          rowsum = (float*)(ws + 53870592);
  unsigned short* Pb     = (unsigned short*)(ws + 53903360);
  const size_t need = 53903360u + (size_t)SEQ * SEQ * 2u;
  if (ws_size < need) return;

  hipMemsetAsync(rowsum, 0, SEQ * sizeof(float), stream);
  hipMemsetAsync(d_out, 0, (size_t)out_size * sizeof(float), stream);

  convert_x<<<SEQ * DMODEL / 1024, 256, 0, stream>>>(x, xb, SEQ * DMODEL / 4);
  convert_w<<<dim3(DMODEL * DMODEL / 1024, 1, 3), 256, 0, stream>>>(
      Wq, Wk, Wv, wqb, wkb, wvb, DMODEL * DMODEL / 4);

  const float alpha_q = 0.03608439182435161f;  // 1/sqrt(768)
  dim3 blk(256);
  // grid.x = M-tiles, grid.y = N-tiles (XCD L2 locality)
  gemm_bt<0><<<dim3(SEQ / 128, DMODEL / 128, 2), blk, 0, stream>>>(
      xb, wqb, Qb, SEQ, DMODEL, DMODEL, alpha_q, nullptr, DMODEL,
      wkb, Kb, 1.0f);
  gemm_bt<0><<<dim3(DMODEL / 128, SEQ / 128, 1), blk, 0, stream>>>(
      wvb, xb, Vtb, DMODEL, SEQ, DMODEL, 1.0f, nullptr, DMODEL,
      nullptr, nullptr, 1.0f);
  gemm_bt<1><<<dim3(SEQ / 128, SEQ / 128, 1), blk, 0, stream>>>(
      Qb, Kb, Pb, SEQ, SEQ, DMODEL, 1.0f, rowsum, DMODEL,
      nullptr, nullptr, 1.0f);
  gemm_bt<2><<<dim3(SEQ / 128, DMODEL / 128, KSPLIT), blk, 0, stream>>>(
      Pb, Vtb, d_out, SEQ, DMODEL, SEQ, 1.0f, rowsum, SEQ / KSPLIT,
      nullptr, nullptr, 1.0f);
}

// Round 5
// 427.128 us; speedup vs baseline: 3.3511x; 3.3511x over previous
//
#include <hip/hip_runtime.h>
#include <stdint.h>

// Self-attention, SEQ=8192, D=768, single head.
//   K0a: x fp32->bf16; K0b: Wq/Wk/Wv fp32->bf16 (z-fused)
//   K1a: Q,K projections z-fused (MODE 0); K1b: Vt = Wv x^T (MODE 0)
//   K2 : P' = exp(Q K^T) bf16 + atomic row sums (MODE 1)
//   K3 : out += (P'_chunk V)/rowsum, split-K x4, fp32 atomicAdd (MODE 2)
//
// R15 = R11 with ONE change: __launch_bounds__(256, 5) -> (256, 4).
// R11/R12 POST-MORTEM (the real one): lb(256,5) forced the allocator under
// ~102 regs while the kernel needs 48 VGPR + 64 acc-AGPR = 112 -> the acc
// tile spilled to scratch INSIDE the K-loop. Scratch goes through TCC:
// WRITE 2.77 GB (vs 147 MB of real output), FETCH 1.7 GB, MfmaUtil 4%,
// K2 1030 us. R11 == R12 despite swizzle-vs-linear source proves the
// source XOR was traffic-neutral (16B-granule XOR within a 128 B row
// requests the same sector set). lb(256,4) -> 128-reg budget, 112 fits,
// same occupancy as the measured-good R10 (4 blk/CU).
// Kept from R11 (correctness-verified there):
//   - global_load_lds width=16 staging (no ds_write VALU cost; m151:
//     874 vs 646 TF vs reg-staged at 128^2)
//   - single 32 KB linear LDS buffer per the m97 2-barrier structure
//   - BOTH-SIDES XOR swizzle (rule #21): linear LDS dest (m104), source
//     column j^(row&7) per-lane (m173), same XOR on ds_read -> ~2-way
//     conflicts (free, m136) instead of 32-way (8.8e7 in R12).

#define SEQ    8192
#define DMODEL 768
#define KSPLIT 4
#define LROW   64            // LDS row stride in halfwords (128 B, linear)

typedef short bf16x8 __attribute__((ext_vector_type(8)));
typedef float f32x4  __attribute__((ext_vector_type(4)));
typedef float f32x16 __attribute__((ext_vector_type(16)));

__device__ __forceinline__ unsigned short f2bf(float f) {
  union { float f; unsigned int u; } v; v.f = f;
  unsigned int u = v.u;
  u += 0x7FFFu + ((u >> 16) & 1u);   // round-to-nearest-even
  return (unsigned short)(u >> 16);
}

// global -> LDS direct DMA, 16 B per lane. LDS dest is wave-uniform base +
// lane*16 (m104); global source address is per-lane (m173), so the swizzle
// lives in the SOURCE column, keeping LDS linear.
__device__ __forceinline__ void gload16(const unsigned short* g, unsigned short* l) {
  __builtin_amdgcn_global_load_lds(
      (const __attribute__((address_space(1))) unsigned int*)g,
      (__attribute__((address_space(3))) unsigned int*)l, 16, 0, 0);
}

__global__ void convert_x(const float* __restrict__ src,
                          unsigned short* __restrict__ dst, int n4) {
  int i = blockIdx.x * blockDim.x + threadIdx.x;
  if (i >= n4) return;
  const float4 f = ((const float4*)src)[i];
  ushort4 o;
  o.x = f2bf(f.x); o.y = f2bf(f.y); o.z = f2bf(f.z); o.w = f2bf(f.w);
  ((ushort4*)dst)[i] = o;
}

__global__ void convert_w(const float* __restrict__ s0, const float* __restrict__ s1,
                          const float* __restrict__ s2,
                          unsigned short* __restrict__ d0, unsigned short* __restrict__ d1,
                          unsigned short* __restrict__ d2, int n4) {
  const float* s = (blockIdx.z == 0) ? s0 : (blockIdx.z == 1) ? s1 : s2;
  unsigned short* d = (blockIdx.z == 0) ? d0 : (blockIdx.z == 1) ? d1 : d2;
  int i = blockIdx.x * blockDim.x + threadIdx.x;
  if (i >= n4) return;
  const float4 f = ((const float4*)s)[i];
  ushort4 o;
  o.x = f2bf(f.x); o.y = f2bf(f.y); o.z = f2bf(f.z); o.w = f2bf(f.w);
  ((ushort4*)d)[i] = o;
}

// C[m,n] = sum_k A[m,k]*B[n,k]  (A:[M,K], B:[N,K] bf16 row-major)
// GRID: blockIdx.x = M-tile, blockIdx.y = N-tile (same-A blocks -> same XCD)
// BK=64, SINGLE linear LDS buffer [128][64] per tensor (32 KB total).
// K-step: compute(kt) -> barrier (reads done) -> issue 8 gload_lds(kt+1)
//   -> barrier (vmcnt drain; hidden by TLP at 4 blk/CU) -> next.
// Swizzle: LDS[row][j] holds G[row][j ^ (row&7)] (16B-chunk granularity);
// read of G[row][g] -> lds halfword (row*64 + ((g<<3) ^ ((row&7)<<3))).
// MFMA 32x32x16: wave quadrant 64x64 = 2x2 tiles; A-op row=lane&31,
// k=(lane>>5)*8+j; C/D col=lane&31, row=(reg&3)+8*(reg>>2)+4*(lane>>5)
// [m74/m101 HW-verified].
// MODE 0: bf16 C*alpha; z=1 uses B2/Cout2/alpha2 (QK fusion)
// MODE 1: bf16 exp(C) + atomicAdd per-row exp-sums into rowsum
// MODE 2: split-K over z (kChunk each); atomicAdd fp32 C/rowsum[m] into Cout
template <int MODE>
__launch_bounds__(256, 4)
__global__ void gemm_bt(const unsigned short* __restrict__ A,
                        const unsigned short* __restrict__ B,
                        void* __restrict__ Cout,
                        int M, int N, int K, float alpha,
                        float* __restrict__ rowsum, int kChunk,
                        const unsigned short* __restrict__ B2,
                        void* __restrict__ Cout2, float alpha2) {
  __shared__ __align__(16) unsigned short lA[128 * LROW];
  __shared__ __align__(16) unsigned short lB[128 * LROW];

  if (MODE == 0) {
    if (blockIdx.z == 1) { B = B2; Cout = Cout2; alpha = alpha2; }
  }
  const int kOff = (MODE == 2) ? blockIdx.z * kChunk : 0;

  const int t    = threadIdx.x;
  const int w    = t >> 6;
  const int l    = t & 63;
  const int r32  = l & 31;     // row within a 32-tile / output col
  const int kh   = l >> 5;     // k-half selector
  const int m0   = blockIdx.x * 128;
  const int n0   = blockIdx.y * 128;
  const int wm   = (w & 1) * 64;
  const int wn   = (w >> 1) * 64;

  // Staging map: 1024 16B-chunks per tensor, 4/thread. c = t + h*256:
  // row = c>>3, 16B-slot j = c&7. LDS dest is LINEAR (chunk c -> c*16 B,
  // wave-uniform base + lane*16). Global SOURCE column is pre-swizzled:
  // slot j fetches G[row][j ^ (row&7)] (traffic-neutral within a 128B row).
  int gOff[4], dOff[4];
#pragma unroll
  for (int h = 0; h < 4; ++h) {
    int c   = t + (h << 8);
    int row = c >> 3;
    int j   = c & 7;
    gOff[h] = row * K + ((j ^ (row & 7)) << 3);  // + m0*K/n0*K in base ptrs
    dOff[h] = c << 3;                            // linear halfword offset
  }
  const unsigned short* Abase = A + (size_t)m0 * K + kOff;
  const unsigned short* Bbase = B + (size_t)n0 * K + kOff;

  // K-invariant swizzled read offsets (halfwords), hoisted out of the loop.
  // row&7 == r32&7 for all four row classes (wm, wn, 32 are multiples of 8).
  const int xr = (r32 & 7) << 3;
  int offA0[4], offA1[4], offB0[4], offB1[4];
#pragma unroll
  for (int ks = 0; ks < 4; ++ks) {
    const int gg = (((ks << 1) | kh) << 3) ^ xr;
    offA0[ks] = (wm      + r32) * LROW + gg;
    offA1[ks] = (wm + 32 + r32) * LROW + gg;
    offB0[ks] = (wn      + r32) * LROW + gg;
    offB1[ks] = (wn + 32 + r32) * LROW + gg;
  }

  f32x16 acc[2][2] = {};
  const int nk = kChunk >> 6;

  // Prologue: DMA tile 0, drain, go.
#pragma unroll
  for (int h = 0; h < 4; ++h) gload16(Abase + gOff[h], &lA[dOff[h]]);
#pragma unroll
  for (int h = 0; h < 4; ++h) gload16(Bbase + gOff[h], &lB[dOff[h]]);
  __syncthreads();                      // vmcnt(0) drain -> tile 0 resident

  for (int kt = 0; kt < nk; ++kt) {
#pragma unroll
    for (int ks = 0; ks < 4; ++ks) {
      bf16x8 a0 = *(const bf16x8*)&lA[offA0[ks]];
      bf16x8 a1 = *(const bf16x8*)&lA[offA1[ks]];
      bf16x8 b0 = *(const bf16x8*)&lB[offB0[ks]];
      bf16x8 b1 = *(const bf16x8*)&lB[offB1[ks]];
      acc[0][0] = __builtin_amdgcn_mfma_f32_32x32x16_bf16(a0, b0, acc[0][0], 0, 0, 0);
      acc[0][1] = __builtin_amdgcn_mfma_f32_32x32x16_bf16(a0, b1, acc[0][1], 0, 0, 0);
      acc[1][0] = __builtin_amdgcn_mfma_f32_32x32x16_bf16(a1, b0, acc[1][0], 0, 0, 0);
      acc[1][1] = __builtin_amdgcn_mfma_f32_32x32x16_bf16(a1, b1, acc[1][1], 0, 0, 0);
    }
    if (kt + 1 < nk) {
      __syncthreads();                  // all reads of the buffer done
      const int ko = (kt + 1) << 6;
#pragma unroll
      for (int h = 0; h < 4; ++h) gload16(Abase + gOff[h] + ko, &lA[dOff[h]]);
#pragma unroll
      for (int h = 0; h < 4; ++h) gload16(Bbase + gOff[h] + ko, &lB[dOff[h]]);
      __syncthreads();                  // vmcnt drain -> tile kt+1 resident
    }
  }

  // C/D 32x32 (m74/m101): col = lane&31, row = (reg&3) + 8*(reg>>2) + 4*kh
  if (MODE == 0) {
    unsigned short* C = (unsigned short*)Cout;
#pragma unroll
    for (int mi = 0; mi < 2; ++mi)
#pragma unroll
      for (int reg = 0; reg < 16; ++reg) {
        int m = m0 + wm + mi * 32 + (reg & 3) + ((reg >> 2) << 3) + (kh << 2);
#pragma unroll
        for (int ni = 0; ni < 2; ++ni) {
          int n = n0 + wn + ni * 32 + r32;
          C[(size_t)m * N + n] = f2bf(acc[mi][ni][reg] * alpha);
        }
      }
  } else if (MODE == 1) {
    unsigned short* C = (unsigned short*)Cout;
#pragma unroll
    for (int mi = 0; mi < 2; ++mi)
#pragma unroll
      for (int reg = 0; reg < 16; ++reg) {
        int m = m0 + wm + mi * 32 + (reg & 3) + ((reg >> 2) << 3) + (kh << 2);
        float s = 0.f;
#pragma unroll
        for (int ni = 0; ni < 2; ++ni) {
          int n = n0 + wn + ni * 32 + r32;
          float p = __expf(acc[mi][ni][reg]);
          C[(size_t)m * N + n] = f2bf(p);
          s += p;
        }
        // reduce over the 32 lanes (r32) sharing this row
#pragma unroll
        for (int off = 1; off < 32; off <<= 1) s += __shfl_xor(s, off, 64);
        if (r32 == 0) atomicAdd(&rowsum[m], s);
      }
  } else {
    float* C = (float*)Cout;   // d_out fp32, zero-initialized; split-K partials
#pragma unroll
    for (int mi = 0; mi < 2; ++mi)
#pragma unroll
      for (int reg = 0; reg < 16; ++reg) {
        int m = m0 + wm + mi * 32 + (reg & 3) + ((reg >> 2) << 3) + (kh << 2);
        float inv = 1.0f / rowsum[m];
#pragma unroll
        for (int ni = 0; ni < 2; ++ni) {
          int n = n0 + wn + ni * 32 + r32;
          atomicAdd(&C[(size_t)m * N + n], acc[mi][ni][reg] * inv);
        }
      }
  }
}

extern "C" void kernel_launch(void* const* d_in, const int* in_sizes, int n_in,
                              void* d_out, int out_size, void* d_ws, size_t ws_size,
                              hipStream_t stream) {
  const float* x  = (const float*)d_in[0];
  const float* Wq = (const float*)d_in[1];
  const float* Wk = (const float*)d_in[2];
  const float* Wv = (const float*)d_in[3];

  char* ws = (char*)d_ws;
  unsigned short* xb     = (unsigned short*)(ws + 0);
  unsigned short* Qb     = (unsigned short*)(ws + 12582912);
  unsigned short* Kb     = (unsigned short*)(ws + 25165824);
  unsigned short* Vtb    = (unsigned short*)(ws + 37748736);
  unsigned short* wqb    = (unsigned short*)(ws + 50331648);
  unsigned short* wkb    = (unsigned short*)(ws + 51511296);
  unsigned short* wvb    = (unsigned short*)(ws + 52690944);
  float*          rowsum = (float*)(ws + 53870592);
  unsigned short* Pb     = (unsigned short*)(ws + 53903360);
  const size_t need = 53903360u + (size_t)SEQ * SEQ * 2u;
  if (ws_size < need) return;

  hipMemsetAsync(rowsum, 0, SEQ * sizeof(float), stream);
  hipMemsetAsync(d_out, 0, (size_t)out_size * sizeof(float), stream);

  convert_x<<<SEQ * DMODEL / 1024, 256, 0, stream>>>(x, xb, SEQ * DMODEL / 4);
  convert_w<<<dim3(DMODEL * DMODEL / 1024, 1, 3), 256, 0, stream>>>(
      Wq, Wk, Wv, wqb, wkb, wvb, DMODEL * DMODEL / 4);

  const float alpha_q = 0.03608439182435161f;  // 1/sqrt(768)
  dim3 blk(256);
  // grid.x = M-tiles, grid.y = N-tiles (XCD L2 locality)
  gemm_bt<0><<<dim3(SEQ / 128, DMODEL / 128, 2), blk, 0, stream>>>(
      xb, wqb, Qb, SEQ, DMODEL, DMODEL, alpha_q, nullptr, DMODEL,
      wkb, Kb, 1.0f);
  gemm_bt<0><<<dim3(DMODEL / 128, SEQ / 128, 1), blk, 0, stream>>>(
      wvb, xb, Vtb, DMODEL, SEQ, DMODEL, 1.0f, nullptr, DMODEL,
      nullptr, nullptr, 1.0f);
  gemm_bt<1><<<dim3(SEQ / 128, SEQ / 128, 1), blk, 0, stream>>>(
      Qb, Kb, Pb, SEQ, SEQ, DMODEL, 1.0f, rowsum, DMODEL,
      nullptr, nullptr, 1.0f);
  gemm_bt<2><<<dim3(SEQ / 128, DMODEL / 128, KSPLIT), blk, 0, stream>>>(
      Pb, Vtb, d_out, SEQ, DMODEL, SEQ, 1.0f, rowsum, SEQ / KSPLIT,
      nullptr, nullptr, 1.0f);
}